// Round 7
// baseline (23.023 us; speedup 1.0000x reference)
//
#include <hip/hip_runtime.h>

#define N_TOTAL 4194304   // 2048*256*8
#define B_SIZE  2048
#define L_SIZE  256
#define I_DIM   8
#define H       32
#define K1_BLK  256       // K1: 256 blocks x 1024 threads
#define K2_BLK  256       // K2: 256 blocks x 1024 threads (8 rows/block, 2 waves/row)

// ws layout in doubles:
//   [2*i], [2*i+1]  i<256 : K1 per-block (sum, sumsq) — compact, coalesced
//   [1024 .. 1039]        : 32 floats of raw (stats-independent) constants
//   [1040]                : u64 packed accumulator (low 56b fixed loss, high 8b arrivals)
#define CRAW_OFF 1024
#define ACC_OFF  1040
#define FIXSCALE 4294967296.0   // 2^32
#define MASK56   0x00FFFFFFFFFFFFFFull

// ================= K1: X pass (stats partials) + raw constant fold =================
__global__ __launch_bounds__(1024) void k1_stats(
    const float4* __restrict__ X4,
    const float* __restrict__ W1, const float* __restrict__ cls,
    const float* __restrict__ Wq, const float* __restrict__ Wk,
    const float* __restrict__ Wv, const float* __restrict__ Wt,
    const float* __restrict__ W2, double* __restrict__ dws)
{
    const int t = threadIdx.x, b = blockIdx.x;
    const int lane = t & 63, wid = t >> 6;      // 16 waves
    const int g = b * 1024 + t;                 // 262144 threads, 4 float4 each

    float s1 = 0.f, s2 = 0.f;
    #pragma unroll
    for (int i = 0; i < 4; i++) {
        float4 v = X4[g + i * 262144];
        s1 += v.x + v.y + v.z + v.w;
        s2 += v.x * v.x + v.y * v.y + v.z * v.z + v.w * v.w;
    }
    for (int off = 32; off; off >>= 1) {
        s1 += __shfl_down(s1, off);
        s2 += __shfl_down(s2, off);
    }
    __shared__ float a1[16], a2[16];
    if (lane == 0) { a1[wid] = s1; a2[wid] = s2; }
    __syncthreads();
    if (t == 0) {
        float r1 = 0.f, r2 = 0.f;
        #pragma unroll
        for (int i = 0; i < 16; i++) { r1 += a1[i]; r2 += a2[i]; }
        dws[2 * b]     = (double)r1;
        dws[2 * b + 1] = (double)r2;
    }

    // ---- block 0: stats-independent raw constants + accumulator zero ----
    if (b == 0) {
        __shared__ float qv[H], kcls[H], vcls[H], tv[H], gg[H], WV[I_DIM][H];
        const float rs32 = 0.17677669529663687f;  // 1/sqrt(32)
        float* craw = (float*)(dws + CRAW_OFF);
        if (t < H) {
            const int h = t;
            float q_ = 0.f, k_ = 0.f, v_ = 0.f, t_ = 0.f;
            for (int j = 0; j < H; j++) {
                float cj = cls[j];
                q_ += cj * Wq[j * H + h];
                k_ += cj * Wk[j * H + h];
                v_ += cj * Wv[j * H + h];
                t_ += cj * Wt[j * H + h];
            }
            qv[h] = q_; kcls[h] = k_; vcls[h] = v_; tv[h] = t_;
        }
        __syncthreads();
        if (t < H) {
            const int h = t;
            float g_ = 0.f;
            for (int j = 0; j < H; j++) g_ += Wk[h * H + j] * qv[j];
            gg[h] = g_;
            for (int i = 0; i < I_DIM; i++) {
                float a = 0.f;
                for (int j = 0; j < H; j++) a += W1[i * H + j] * Wv[j * H + h];
                WV[i][h] = a;
            }
        }
        __syncthreads();
        if (t < I_DIM) {                       // u_raw
            float a = 0.f;
            for (int j = 0; j < H; j++) a += W1[t * H + j] * gg[j];
            craw[t] = a;
        }
        if (t < I_DIM * 2) {                   // M_raw
            const int i = t >> 1, o = t & 1;
            float a = 0.f;
            for (int j = 0; j < H; j++) a += WV[i][j] * W2[j * 2 + o];
            craw[10 + i * 2 + o] = a;
        }
        if (t == 0) {
            float c2 = 0.f;
            for (int j = 0; j < H; j++) c2 += qv[j] * kcls[j];
            craw[9] = c2 * rs32;
            float vw0 = 0.f, vw1 = 0.f, tw0 = 0.f, tw1 = 0.f;
            for (int j = 0; j < H; j++) {
                vw0 += vcls[j] * W2[j * 2];     vw1 += vcls[j] * W2[j * 2 + 1];
                tw0 += tv[j]   * W2[j * 2];     tw1 += tv[j]   * W2[j * 2 + 1];
            }
            craw[28] = vw0; craw[29] = vw1; craw[30] = tw0; craw[31] = tw1;
            *(unsigned long long*)(dws + ACC_OFF) = 0ull;   // reset packed accumulator
        }
    }
}

// ========== K2: 1024 thr, 8 rows/block, 2 waves/row + packed-atomic finalize ==========
__global__ __launch_bounds__(1024) void k2_attn(
    const float* __restrict__ X, const int* __restrict__ y,
    double* __restrict__ dws, float* __restrict__ out)
{
    const int t = threadIdx.x, b = blockIdx.x;
    const int lane = t & 63, w = t >> 6;       // 16 waves
    const int lr = w >> 1, half = w & 1;       // local row 0..7, half 0/1
    const int r = b * 8 + lr;                  // global row

    // ---- issue X loads first (independent of everything) ----
    const float4* Xb = (const float4*)X + (size_t)r * 512;
    const int p0 = half * 128 + lane;          // my two positions: p0, p0+64
    float4 A = Xb[2 * p0],        Bv = Xb[2 * p0 + 1];
    float4 C = Xb[2 * (p0 + 64)], D  = Xb[2 * (p0 + 64) + 1];

    // ---- stats reduce: 256 compact slots, waves 0-3 ----
    __shared__ double da[4], db[4];
    if (t < 256) {
        double d1 = dws[2 * t], d2 = dws[2 * t + 1];
        for (int off = 32; off; off >>= 1) {
            d1 += __shfl_down(d1, off);
            d2 += __shfl_down(d2, off);
        }
        if (lane == 0) { da[w] = d1; db[w] = d2; }
    }
    __syncthreads();

    __shared__ float sNegMu, sSdev;
    if (t == 0) {
        double S1 = da[0] + da[1] + da[2] + da[3];
        double S2 = db[0] + db[1] + db[2] + db[3];
        double mu = S1 / (double)N_TOTAL;
        double var = (S2 - S1 * S1 / (double)N_TOTAL) / (double)(N_TOTAL - 1);
        sSdev = (float)(sqrt(var) + 1e-7);
        sNegMu = (float)(-mu);
    }
    __syncthreads();

    // ---- scale raw constants into LDS cst[32] ----
    __shared__ float cst[32];
    const float* craw = (const float*)(dws + CRAW_OFF);
    const float rs32 = 0.17677669529663687f;
    if (t < 32) {
        const float sdev = sSdev, negmu = sNegMu;
        if (t < 8) {
            cst[t] = craw[t] / sdev * rs32;
        } else if (t == 8) {
            float cs = 0.f;
            for (int i = 0; i < 8; i++) cs += craw[i] / sdev * rs32;
            cst[8] = negmu * cs;
        } else if (t == 9) {
            cst[9] = craw[9];
        } else if (t < 26) {
            cst[t] = craw[t] / sdev;
        } else if (t == 26) {
            float m0 = 0.f;
            for (int i = 0; i < 8; i++) m0 += craw[10 + 2 * i] / sdev;
            cst[26] = negmu * m0;
        } else if (t == 27) {
            float m1 = 0.f;
            for (int i = 0; i < 8; i++) m1 += craw[11 + 2 * i] / sdev;
            cst[27] = negmu * m1;
        } else {
            cst[t] = craw[t];
        }
    }
    __syncthreads();

    // ---- scores for my 2 positions ----
    float x0[8] = {A.x, A.y, A.z, A.w, Bv.x, Bv.y, Bv.z, Bv.w};
    float x1[8] = {C.x, C.y, C.z, C.w, D.x,  D.y,  D.z,  D.w};
    const float c8 = cst[8];
    float sc0 = c8, sc1 = c8;
    #pragma unroll
    for (int i = 0; i < 8; i++) {
        sc0 += x0[i] * cst[i];
        sc1 += x1[i] * cst[i];
    }

    // ---- row max: wave reduce, then combine the 2 half-waves via LDS ----
    __shared__ float rmax[8][2];
    __shared__ float rsum[8][2][9];
    __shared__ double wloss[8];
    float mw = fmaxf(sc0, sc1);
    for (int off = 32; off; off >>= 1) mw = fmaxf(mw, __shfl_xor(mw, off));
    if (lane == 0) rmax[lr][half] = mw;
    __syncthreads();
    const float m = fmaxf(fmaxf(rmax[lr][0], rmax[lr][1]), cst[9]);

    // ---- weighted partial sums ----
    float e0 = expf(sc0 - m), e1 = expf(sc1 - m);
    float v[9];
    v[0] = e0 + e1;
    #pragma unroll
    for (int i = 0; i < 8; i++) v[i + 1] = e0 * x0[i] + e1 * x1[i];
    for (int off = 32; off; off >>= 1) {
        #pragma unroll
        for (int j = 0; j < 9; j++) v[j] += __shfl_down(v[j], off);
    }
    if (lane == 0) {
        #pragma unroll
        for (int j = 0; j < 9; j++) rsum[lr][half][j] = v[j];
    }
    __syncthreads();

    // ---- per-row epilogue: 8 threads, one row each ----
    if (t < 8) {
        float vv[9];
        #pragma unroll
        for (int j = 0; j < 9; j++) vv[j] = rsum[t][0][j] + rsum[t][1][j];
        float mrow = fmaxf(fmaxf(rmax[t][0], rmax[t][1]), cst[9]);
        float ecls = expf(cst[9] - mrow);
        float inv = 1.f / (vv[0] + ecls);
        float S256 = ecls * inv;
        float z[2];
        #pragma unroll
        for (int o = 0; o < 2; o++) {
            float a = 0.f;
            #pragma unroll
            for (int i = 0; i < 8; i++)
                a += (vv[i + 1] * inv) * cst[10 + i * 2 + o];
            z[o] = a + (1.f - S256) * cst[26 + o] + S256 * cst[28 + o] + cst[30 + o];
        }
        float zm = fmaxf(z[0], z[1]);
        float lse = zm + logf(expf(z[0] - zm) + expf(z[1] - zm));
        int yb = y[b * 8 + t];
        wloss[t] = (double)(lse - z[yb]);
    }
    __syncthreads();

    // ---- one packed relaxed RMW per block ----
    if (t == 0) {
        double blockloss = 0.0;
        #pragma unroll
        for (int i = 0; i < 8; i++) blockloss += wloss[i];
        unsigned long long fixed =
            (unsigned long long)(blockloss * FIXSCALE + 0.5);
        unsigned long long* acc = (unsigned long long*)(dws + ACC_OFF);
        unsigned long long old = __hip_atomic_fetch_add(
            acc, fixed + (1ull << 56), __ATOMIC_RELAXED, __HIP_MEMORY_SCOPE_AGENT);
        if ((old >> 56) == (unsigned long long)(K2_BLK - 1)) {  // last block
            unsigned long long total = ((old & MASK56) + fixed) & MASK56;
            out[0] = (float)((double)total / FIXSCALE / (double)B_SIZE);
        }
    }
}

extern "C" void kernel_launch(void* const* d_in, const int* in_sizes, int n_in,
                              void* d_out, int out_size, void* d_ws, size_t ws_size,
                              hipStream_t stream) {
    const float* X   = (const float*)d_in[0];
    const int*   y   = (const int*)d_in[1];
    const float* W1  = (const float*)d_in[2];
    const float* cls = (const float*)d_in[3];
    const float* Wq  = (const float*)d_in[4];
    const float* Wk  = (const float*)d_in[5];
    const float* Wv  = (const float*)d_in[6];
    const float* Wt  = (const float*)d_in[7];
    const float* W2  = (const float*)d_in[8];
    float* out = (float*)d_out;
    double* dws = (double*)d_ws;

    hipLaunchKernelGGL(k1_stats, dim3(K1_BLK), dim3(1024), 0, stream,
                       (const float4*)X, W1, cls, Wq, Wk, Wv, Wt, W2, dws);
    hipLaunchKernelGGL(k2_attn, dim3(K2_BLK), dim3(1024), 0, stream,
                       X, y, dws, out);
}